// Round 4
// baseline (1444.588 us; speedup 1.0000x reference)
//
#include <hip/hip_runtime.h>
#include <math.h>

// Problem constants
constexpr int Cc = 128;          // channels
constexpr int Dd = 48, Hh = 48, Ww = 48;
constexpr int SP = Dd * Hh * Ww; // 110592 voxels per batch
constexpr int NV = 2 * SP;       // 221184 total voxels
constexpr float EPSV = 1e-5f;

typedef __attribute__((ext_vector_type(8))) short short8;
typedef __attribute__((ext_vector_type(4))) float f32x4;

static __device__ __forceinline__ ushort f2bf(float f) {
    uint u = __float_as_uint(f);
    uint r = (u + 0x7fffu + ((u >> 16) & 1u)) >> 16;   // RNE
    return (ushort)r;
}

// ---------------------------------------------------------------- prep
// wtb bf16 [o][c] (o<64 theta, <128 phi, else G); rwb bf16 [c][g]; zero bnacc.
__global__ void k_prep(const float* __restrict__ th, const float* __restrict__ ph,
                       const float* __restrict__ gw, const float* __restrict__ rw,
                       ushort* __restrict__ wtb, ushort* __restrict__ rwb,
                       float* __restrict__ bnacc) {
    int tid = threadIdx.x;
    for (int i = tid; i < 192 * 128; i += 256) {
        int o = i >> 7, c = i & 127;
        float v = (o < 64)  ? th[o * 128 + c]
                : (o < 128) ? ph[(o - 64) * 128 + c]
                            : gw[(o - 128) * 128 + c];
        wtb[i] = f2bf(v);
    }
    for (int i = tid; i < 128 * 64; i += 256) rwb[i] = f2bf(rw[i]);
    if (tid < 256) bnacc[tid] = 0.f;
}

// ---------------------------------------------------------------- projections (MFMA)
__global__ __launch_bounds__(256) void k_proj(
        const float* __restrict__ h, const ushort* __restrict__ wtb,
        const float* __restrict__ tb, const float* __restrict__ pb,
        const float* __restrict__ gb,
        ushort* __restrict__ tO, ushort* __restrict__ pO, ushort* __restrict__ gO) {
    __shared__ __align__(16) uint wl[192 * 64];   // 48 KB, [o][c-pairs] swizzled
    int tid = threadIdx.x;
    const uint* wu = (const uint*)wtb;
    for (int i = tid; i < 192 * 64; i += 256) {
        int o = i >> 6, dw = i & 63;
        wl[(o << 6) + ((((dw >> 2) ^ (o & 15)) << 2)) + (dw & 3)] = wu[i];
    }
    int blk = blockIdx.x;                         // 3456
    int b = blk / (SP / 64);
    int vsp0 = (blk % (SP / 64)) * 64;
    const float* hb = h + (size_t)b * Cc * SP;
    int lane = tid & 63, wv = tid >> 6;
    int m = lane & 15, quad = lane >> 4;
    int vg = vsp0 + wv * 16 + m;
    short8 afr[4];
#pragma unroll
    for (int ks = 0; ks < 4; ++ks) {
        int c0 = ks * 32 + quad * 8;
        float xv[8];
#pragma unroll
        for (int j = 0; j < 8; ++j) xv[j] = hb[(size_t)(c0 + j) * SP + vg];
        union { short8 v; ushort e[8]; } u;
#pragma unroll
        for (int j = 0; j < 8; ++j) u.e[j] = f2bf(xv[j]);
        afr[ks] = u.v;
    }
    __syncthreads();
    int vox = b * SP + vsp0 + wv * 16 + quad * 4;
#pragma unroll 1
    for (int nt = 0; nt < 12; ++nt) {
        int o16 = (nt & 3) * 16 + m;
        float bv = (nt < 4) ? tb[o16] : (nt < 8) ? pb[o16] : gb[o16];
        f32x4 acc = {bv, bv, bv, bv};
        int o = nt * 16 + m;
#pragma unroll
        for (int ks = 0; ks < 4; ++ks) {
            int chunk = ks * 4 + quad;
            short8 bfr = *(const short8*)&wl[(o << 6) + ((chunk ^ (o & 15)) << 2)];
            acc = __builtin_amdgcn_mfma_f32_16x16x32_bf16(afr[ks], bfr, acc, 0, 0, 0);
        }
        ushort* ob = (nt < 4) ? tO : (nt < 8) ? pO : gO;
#pragma unroll
        for (int r = 0; r < 4; ++r) ob[(size_t)(vox + r) * 64 + o16] = f2bf(acc[r]);
    }
}

// ---------------------------------------------------------------- scores (MFMA, 3 axes)
__global__ __launch_bounds__(256) void k_scores(
        const ushort* __restrict__ t, const ushort* __restrict__ p,
        float* __restrict__ fbase) {
    __shared__ __align__(16) uint sl[4 * 3072];
    int blk = blockIdx.x;                         // 3456 = 3 axes * 1152
    int axis = blk / 1152, rem = blk % 1152;
    int wv = threadIdx.x >> 6, lane = threadIdx.x & 63;
    int L = rem * 4 + wv;
    int b = L / 2304, rr = L % 2304, i = rr / 48, j = rr % 48;
    int stride, vsp0;
    if (axis == 0)      { stride = 2304; vsp0 = i * 48 + j; }
    else if (axis == 1) { stride = 48;   vsp0 = i * 2304 + j; }
    else                { stride = 1;    vsp0 = i * 2304 + j * 48; }
    int vox0 = b * SP + vsp0;
    float* f = fbase + (size_t)axis * NV * 48;
    uint* tl = &sl[wv * 3072];
    uint* pl = tl + 1536;
    const uint* tu = (const uint*)t;
    const uint* pu = (const uint*)p;
#pragma unroll 4
    for (int it = 0; it < 24; ++it) {
        int idx = it * 64 + lane;
        int r = idx >> 5, dw = idx & 31;
        int gaddr = (vox0 + r * stride) * 32 + dw;
        int laddr = (r << 5) + (((dw >> 2) ^ (r & 7)) << 2) + (dw & 3);
        tl[laddr] = tu[gaddr];
        pl[laddr] = pu[gaddr];
    }
    __syncthreads();
    int m = lane & 15, quad = lane >> 4;
    short8 afr[3][2];
#pragma unroll
    for (int mt = 0; mt < 3; ++mt)
#pragma unroll
        for (int ks = 0; ks < 2; ++ks) {
            int r = mt * 16 + m, chunk = ks * 4 + quad;
            afr[mt][ks] = *(const short8*)&tl[(r << 5) + ((chunk ^ (r & 7)) << 2)];
        }
    f32x4 acc[3][3];
#pragma unroll
    for (int mt = 0; mt < 3; ++mt)
#pragma unroll
        for (int nt = 0; nt < 3; ++nt) acc[mt][nt] = (f32x4){0.f, 0.f, 0.f, 0.f};
#pragma unroll
    for (int nt = 0; nt < 3; ++nt)
#pragma unroll
        for (int ks = 0; ks < 2; ++ks) {
            int a = nt * 16 + m, chunk = ks * 4 + quad;
            short8 bfr = *(const short8*)&pl[(a << 5) + ((chunk ^ (a & 7)) << 2)];
#pragma unroll
            for (int mt = 0; mt < 3; ++mt)
                acc[mt][nt] = __builtin_amdgcn_mfma_f32_16x16x32_bf16(
                    afr[mt][ks], bfr, acc[mt][nt], 0, 0, 0);
        }
    bool mask = (axis != 0);
#pragma unroll
    for (int mt = 0; mt < 3; ++mt)
#pragma unroll
        for (int nt = 0; nt < 3; ++nt)
#pragma unroll
            for (int r4 = 0; r4 < 4; ++r4) {
                int r = mt * 16 + quad * 4 + r4;
                int a = nt * 16 + m;
                float v = acc[mt][nt][r4];
                if (mask && a == r) v = -1e30f;
                f[(size_t)(vox0 + r * stride) * 48 + a] = v;
            }
}

// ---------------------------------------------------------------- softmax (in-place fp32)
__global__ __launch_bounds__(256) void k_softmax(
        float* __restrict__ fD, float* __restrict__ fH, float* __restrict__ fW) {
    int wv = threadIdx.x >> 6, lane = threadIdx.x & 63;
    long vox = (long)blockIdx.x * 4 + wv;
    float* b0 = fD + vox * 48;
    float* b1 = fH + vox * 48;
    float* b2 = fW + vox * 48;
    float v0 = (lane < 48) ? b0[lane] : b1[lane - 48];
    float v1 = (lane < 32) ? b1[lane + 16] : b2[lane - 32];
    float v2 = (lane < 16) ? b2[lane + 32] : -1e30f;
    float m = fmaxf(v0, fmaxf(v1, v2));
#pragma unroll
    for (int o = 32; o; o >>= 1) m = fmaxf(m, __shfl_xor(m, o, 64));
    float e0 = __expf(v0 - m);
    float e1 = __expf(v1 - m);
    float e2 = (lane < 16) ? __expf(v2 - m) : 0.f;
    float s = e0 + e1 + e2;
#pragma unroll
    for (int o = 32; o; o >>= 1) s += __shfl_xor(s, o, 64);
    float inv = 1.f / s;
    if (lane < 48) b0[lane] = e0 * inv; else b1[lane - 48] = e0 * inv;
    if (lane < 32) b1[lane + 16] = e1 * inv; else b2[lane - 32] = e1 * inv;
    if (lane < 16) b2[lane + 32] = e2 * inv;
}

// ---------------------------------------------------------------- weighted sum (MFMA)
__global__ __launch_bounds__(128) void k_ysum(
        const float* __restrict__ wgt, const ushort* __restrict__ g,
        float* __restrict__ y, int axis, int accum) {
    __shared__ __align__(16) uint sl[2 * 3584];   // per-wave wl 1536 + gl 2048 dw
    int wv = threadIdx.x >> 6, lane = threadIdx.x & 63;
    uint* wl = &sl[wv * 3584];
    uint* gl = wl + 1536;
    int L = blockIdx.x * 2 + wv;                  // 0..4607
    int b = L / 2304, rr = L % 2304, i = rr / 48, j = rr % 48;
    int stride, vsp0;
    if (axis == 0)      { stride = 2304; vsp0 = i * 48 + j; }
    else if (axis == 1) { stride = 48;   vsp0 = i * 2304 + j; }
    else                { stride = 1;    vsp0 = i * 2304 + j * 48; }
    int vox0 = b * SP + vsp0;
#pragma unroll 4
    for (int it = 0; it < 24; ++it) {
        int idx = it * 64 + lane;
        int r = idx >> 5, dw = idx & 31;
        uint pk = 0;
        if (dw < 24) {
            const float* src = wgt + (size_t)(vox0 + r * stride) * 48 + dw * 2;
            pk = (uint)f2bf(src[0]) | ((uint)f2bf(src[1]) << 16);
        }
        wl[(r << 5) + (((dw >> 2) ^ (r & 7)) << 2) + (dw & 3)] = pk;
    }
#pragma unroll
    for (int it = 0; it < 8; ++it) {
        int idx = it * 64 + lane;
        int s = idx >> 3, dwp = 24 + (idx & 7);
        gl[(s << 5) + ((((dwp >> 2)) ^ (s & 7)) << 2) + (dwp & 3)] = 0;
    }
    const uint* gu = (const uint*)g;
#pragma unroll 4
    for (int it = 0; it < 24; ++it) {
        int a = it * 2 + (lane >> 5);
        int dw = lane & 31;
        uint v = gu[(size_t)(vox0 + a * stride) * 32 + dw];
        uint w = (uint)__shfl_xor((int)v, 32, 64);
        uint dst; int s;
        if (lane < 32) { s = dw * 2;     dst = (v & 0xffffu) | (w << 16); }
        else           { s = dw * 2 + 1; dst = (w >> 16) | (v & 0xffff0000u); }
        int adw = it;
        gl[(s << 5) + ((((adw >> 2)) ^ (s & 7)) << 2) + (adw & 3)] = dst;
    }
    int m = lane & 15, quad = lane >> 4;
    short8 afr[3][2];
#pragma unroll
    for (int mt = 0; mt < 3; ++mt)
#pragma unroll
        for (int ks = 0; ks < 2; ++ks) {
            int r = mt * 16 + m, chunk = ks * 4 + quad;
            afr[mt][ks] = *(const short8*)&wl[(r << 5) + ((chunk ^ (r & 7)) << 2)];
        }
    f32x4 acc[3][4];
#pragma unroll
    for (int mt = 0; mt < 3; ++mt)
#pragma unroll
        for (int nt = 0; nt < 4; ++nt) acc[mt][nt] = (f32x4){0.f, 0.f, 0.f, 0.f};
#pragma unroll
    for (int nt = 0; nt < 4; ++nt)
#pragma unroll
        for (int ks = 0; ks < 2; ++ks) {
            int s = nt * 16 + m, chunk = ks * 4 + quad;
            short8 bfr = *(const short8*)&gl[(s << 5) + ((chunk ^ (s & 7)) << 2)];
#pragma unroll
            for (int mt = 0; mt < 3; ++mt)
                acc[mt][nt] = __builtin_amdgcn_mfma_f32_16x16x32_bf16(
                    afr[mt][ks], bfr, acc[mt][nt], 0, 0, 0);
        }
#pragma unroll
    for (int mt = 0; mt < 3; ++mt)
#pragma unroll
        for (int nt = 0; nt < 4; ++nt)
#pragma unroll
            for (int r4 = 0; r4 < 4; ++r4) {
                int r = mt * 16 + quad * 4 + r4;
                size_t addr = (size_t)(vox0 + r * stride) * 64 + nt * 16 + m;
                float pr = accum ? y[addr] : 0.f;
                y[addr] = pr + acc[mt][nt][r4];
            }
}

// ---------------------------------------------------------------- cross proj (MFMA) + GN partials
// cross[b][c][vox] = sum_g y[vox][g]*r_w[c][g] + r_b[c]; per-block GN partial sums.
__global__ __launch_bounds__(256) void k_cross(
        const float* __restrict__ y, const ushort* __restrict__ rwb,
        const float* __restrict__ rb, float* __restrict__ cross,
        float* __restrict__ part) {
    __shared__ __align__(16) uint wl[4096];        // r_w bf16 [c][g-pairs] swizzled
    __shared__ __align__(16) float stg[8192];      // c-major staging, chunk-swizzled
    __shared__ float gnbuf[4 * 64];
    int tid = threadIdx.x;
    const uint* ru = (const uint*)rwb;
    for (int i = tid; i < 4096; i += 256) {
        int c = i >> 5, dwc = i & 31;
        wl[(c << 5) + (((dwc >> 2) ^ (c & 7)) << 2) + (dwc & 3)] = ru[i];
    }
    int blk = blockIdx.x;                          // 3456
    int b = blk / 1728;
    int vsp0 = (blk % 1728) * 64;
    int lane = tid & 63, wv = tid >> 6;
    int m = lane & 15, quad = lane >> 4;
    int vrow = b * SP + vsp0 + wv * 16 + m;
    short8 afr[2];
#pragma unroll
    for (int ks = 0; ks < 2; ++ks) {
        const float* src = y + (size_t)vrow * 64 + ks * 32 + quad * 8;
        union { short8 v; ushort e[8]; } u;
#pragma unroll
        for (int j = 0; j < 8; ++j) u.e[j] = f2bf(src[j]);
        afr[ks] = u.v;
    }
    __syncthreads();
    float gs[8], gss[8];
#pragma unroll
    for (int nt = 0; nt < 8; ++nt) {
        int c = nt * 16 + m;
        float bv = rb[c];
        f32x4 acc = {bv, bv, bv, bv};
#pragma unroll
        for (int ks = 0; ks < 2; ++ks) {
            int chunk = ks * 4 + quad;
            short8 bfr = *(const short8*)&wl[(c << 5) + ((chunk ^ (c & 7)) << 2)];
            acc = __builtin_amdgcn_mfma_f32_16x16x32_bf16(afr[ks], bfr, acc, 0, 0, 0);
        }
        int vc = wv * 4 + quad;
        *(f32x4*)&stg[(c << 6) + ((vc ^ (c & 15)) << 2)] = acc;
        float s = acc[0] + acc[1] + acc[2] + acc[3];
        float ss = acc[0]*acc[0] + acc[1]*acc[1] + acc[2]*acc[2] + acc[3]*acc[3];
        s += __shfl_xor(s, 16, 64); ss += __shfl_xor(ss, 16, 64);
        s += __shfl_xor(s, 32, 64); ss += __shfl_xor(ss, 32, 64);
        s += __shfl_xor(s, 1, 64);  ss += __shfl_xor(ss, 1, 64);
        s += __shfl_xor(s, 2, 64);  ss += __shfl_xor(ss, 2, 64);
        gs[nt] = s; gss[nt] = ss;
    }
    if (quad == 0 && (m & 3) == 0) {
#pragma unroll
        for (int nt = 0; nt < 8; ++nt) {
            int g = nt * 4 + (m >> 2);
            gnbuf[wv * 64 + g * 2]     = gs[nt];
            gnbuf[wv * 64 + g * 2 + 1] = gss[nt];
        }
    }
    __syncthreads();
    if (tid < 64) {
        float v = gnbuf[tid] + gnbuf[64 + tid] + gnbuf[128 + tid] + gnbuf[192 + tid];
        part[(size_t)blk * 64 + tid] = v;
    }
    const size_t base = ((size_t)b * Cc) * SP + vsp0;
#pragma unroll
    for (int it = 0; it < 8; ++it) {
        int idx = it * 256 + tid;
        int c = idx >> 4, v4 = idx & 15;
        f32x4 val = *(const f32x4*)&stg[(c << 6) + ((v4 ^ (c & 15)) << 2)];
        *(f32x4*)&cross[base + (size_t)c * SP + v4 * 4] = val;
    }
}

// ---------------------------------------------------------------- GN finalize
__global__ __launch_bounds__(256) void k_gnfin(const float* __restrict__ part,
                                               float* __restrict__ stats) {
    __shared__ float red[512];
    int tid = threadIdx.x;
    int i = tid >> 2, sl = tid & 3;      // i: global group (b*32+grp)
    int b = i >> 5;
    float s = 0.f, ss = 0.f;
    for (int t = sl; t < 1728; t += 4) {
        const float* p = part + ((size_t)(b * 1728 + t)) * 64 + (i & 31) * 2;
        s += p[0]; ss += p[1];
    }
    red[tid * 2] = s; red[tid * 2 + 1] = ss;
    __syncthreads();
    if (sl == 0) {
        s  = red[tid*2]   + red[(tid+1)*2]   + red[(tid+2)*2]   + red[(tid+3)*2];
        ss = red[tid*2+1] + red[(tid+1)*2+1] + red[(tid+2)*2+1] + red[(tid+3)*2+1];
        float n = 4.f * SP;
        float mu = s / n, var = ss / n - mu * mu;
        stats[i * 2] = mu;
        stats[i * 2 + 1] = rsqrtf(var + EPSV);
    }
}

// ---------------------------------------------------------------- GN apply (+ BN partials on last layer)
__global__ __launch_bounds__(256) void k_gnapply(
        const float* __restrict__ hin, const float* __restrict__ cross,
        const float* __restrict__ stats, const float* __restrict__ gw,
        const float* __restrict__ gb, float* __restrict__ hout,
        float* __restrict__ bnacc, int do_bn) {
    long q = ((long)blockIdx.x * 256 + threadIdx.x) * 4;
    int c = (int)((q / SP) & 127);
    int b = (int)(q / ((long)Cc * SP));
    int bg = b * 32 + (c >> 2);
    float mu = stats[bg * 2], inv = stats[bg * 2 + 1];
    float sc = inv * gw[c], sh = gb[c] - mu * sc;
    float4 cv = *(const float4*)(cross + q);
    float4 hv = *(const float4*)(hin + q);
    float4 o = make_float4(hv.x + cv.x * sc + sh, hv.y + cv.y * sc + sh,
                           hv.z + cv.z * sc + sh, hv.w + cv.w * sc + sh);
    *(float4*)(hout + q) = o;
    if (do_bn) {
        float s = o.x + o.y + o.z + o.w;
        float ss = o.x*o.x + o.y*o.y + o.z*o.z + o.w*o.w;
#pragma unroll
        for (int of = 32; of; of >>= 1) { s += __shfl_xor(s, of, 64); ss += __shfl_xor(ss, of, 64); }
        __shared__ float rs[8];
        int wv = threadIdx.x >> 6;
        if ((threadIdx.x & 63) == 0) { rs[wv * 2] = s; rs[wv * 2 + 1] = ss; }
        __syncthreads();
        if (threadIdx.x == 0) {
            float S = rs[0] + rs[2] + rs[4] + rs[6];
            float SS = rs[1] + rs[3] + rs[5] + rs[7];
            atomicAdd(&bnacc[c * 2], S);
            atomicAdd(&bnacc[c * 2 + 1], SS);
        }
    }
}

// ---------------------------------------------------------------- BN
__global__ void k_bnfin(const float* __restrict__ bnacc, const float* __restrict__ bw,
                        const float* __restrict__ bb, float* __restrict__ ssout) {
    int c = threadIdx.x;
    if (c < 128) {
        float s = bnacc[c * 2], q = bnacc[c * 2 + 1];
        float n = 2.f * SP;
        float mu = s / n, var = q / n - mu * mu;
        float inv = rsqrtf(var + EPSV);
        float a1 = inv * bw[c];
        ssout[c * 2] = a1;
        ssout[c * 2 + 1] = bb[c] - mu * a1;
    }
}

__global__ __launch_bounds__(256) void k_bnrelu(
        const float* __restrict__ h, const float* __restrict__ ssin,
        float* __restrict__ out) {
    long q = ((long)blockIdx.x * 256 + threadIdx.x) * 4;
    int c = (int)((q / SP) & 127);
    float a1 = ssin[c * 2], a0 = ssin[c * 2 + 1];
    float4 v = *(const float4*)(h + q);
    float4 o = make_float4(fmaxf(v.x * a1 + a0, 0.f), fmaxf(v.y * a1 + a0, 0.f),
                           fmaxf(v.z * a1 + a0, 0.f), fmaxf(v.w * a1 + a0, 0.f));
    *(float4*)(out + q) = o;
}

// ---------------------------------------------------------------- launch
extern "C" void kernel_launch(void* const* d_in, const int* in_sizes, int n_in,
                              void* d_out, int out_size, void* d_ws, size_t ws_size,
                              hipStream_t stream) {
    const float* x   = (const float*)d_in[0];
    const float* thw = (const float*)d_in[1];
    const float* thb = (const float*)d_in[2];
    const float* phw = (const float*)d_in[3];
    const float* phb = (const float*)d_in[4];
    const float* gww = (const float*)d_in[5];
    const float* gwb = (const float*)d_in[6];
    const float* rw  = (const float*)d_in[7];
    const float* rb  = (const float*)d_in[8];
    const float* gnw = (const float*)d_in[9];
    const float* gnb = (const float*)d_in[10];
    const float* bnw = (const float*)d_in[11];
    const float* bnb = (const float*)d_in[12];

    float* ws    = (float*)d_ws;
    float* part  = ws;                         // 3456*64 = 221184 floats
    float* stats = ws + 221184;                // 128
    float* bnacc = ws + 221312;                // 256
    float* bnss  = ws + 221568;                // 256
    ushort* rwb  = (ushort*)(ws + 221824);     // 8192 bf16
    ushort* wTb  = (ushort*)(ws + 225920);     // 24576 bf16
    ushort* tB16 = (ushort*)(ws + 238208);     // NV*64 bf16
    ushort* pB16 = tB16 + (size_t)NV * 64;
    ushort* gB16 = pB16 + (size_t)NV * 64;
    float* yB    = ws + 238208 + (3 * (size_t)NV * 64) / 2;  // NV*64 fp32
    float* fbase = yB + (size_t)NV * 64;       // 3*NV*48 fp32
    float* fD = fbase;
    float* fH = fbase + (size_t)NV * 48;
    float* fW = fbase + (size_t)NV * 48 * 2;
    float* crossB = fbase;                     // reuse (f dead after ysum)
    float* out = (float*)d_out;

    k_prep<<<1, 256, 0, stream>>>(thw, phw, gww, rw, wTb, rwb, bnacc);

    const float* hin = x;
    for (int layer = 0; layer < 2; ++layer) {
        k_proj<<<NV / 64, 256, 0, stream>>>(hin, wTb, thb, phb, gwb, tB16, pB16, gB16);
        k_scores<<<3456, 256, 0, stream>>>(tB16, pB16, fbase);
        k_softmax<<<NV / 4, 256, 0, stream>>>(fD, fH, fW);
        for (int ax = 0; ax < 3; ++ax)
            k_ysum<<<2304, 128, 0, stream>>>((ax == 0 ? fD : ax == 1 ? fH : fW),
                gB16, yB, ax, ax > 0);
        k_cross<<<3456, 256, 0, stream>>>(yB, rwb, rb, crossB, part);
        k_gnfin<<<1, 256, 0, stream>>>(part, stats);
        k_gnapply<<<(int)(((long)2 * Cc * SP / 4) / 256), 256, 0, stream>>>(
            hin, crossB, stats, gnw + layer * 128, gnb + layer * 128, out,
            bnacc, layer == 1);
        hin = out;
    }
    k_bnfin<<<1, 128, 0, stream>>>(bnacc, bnw, bnb, bnss);
    k_bnrelu<<<(int)(((long)2 * Cc * SP / 4) / 256), 256, 0, stream>>>(out, bnss, out);
}